// Round 1
// baseline (1411.509 us; speedup 1.0000x reference)
//
#include <hip/hip_runtime.h>
#include <hip/hip_bf16.h>
#include <cstdint>
#include <cstddef>

#define NNODES 50000
#define NEDGES 800000
#define NREL 8
#define DIM 128
#define NEG_SLOPE 0.2f

// ======================= preprocessing: CSR by (dst, etype) =======================

__global__ void k_hist(const int* __restrict__ ei, const int* __restrict__ et,
                       int* __restrict__ cnt, int E) {
  int e = blockIdx.x * 256 + threadIdx.x;
  if (e < E) {
    int d = ei[E + e];
    int t = et[e];
    atomicAdd(&cnt[d * NREL + t], 1);
  }
}

__global__ void k_scan_reduce(const int* __restrict__ cnt, int* __restrict__ sums, int n) {
  __shared__ int sd[256];
  int base = blockIdx.x * 4096;
  int t = threadIdx.x;
  int acc = 0;
  for (int i = t; i < 4096; i += 256) {
    int idx = base + i;
    if (idx < n) acc += cnt[idx];
  }
  sd[t] = acc; __syncthreads();
  for (int s = 128; s > 0; s >>= 1) {
    if (t < s) sd[t] += sd[t + s];
    __syncthreads();
  }
  if (t == 0) sums[blockIdx.x] = sd[0];
}

__global__ void k_scan_top(int* sums, int nb) {
  if (threadIdx.x == 0 && blockIdx.x == 0) {
    int run = 0;
    for (int i = 0; i < nb; i++) { int v = sums[i]; sums[i] = run; run += v; }
  }
}

__global__ void k_scan_final(const int* __restrict__ cnt, const int* __restrict__ sums,
                             int* __restrict__ offs, int n, int E) {
  __shared__ int sd[256];
  int base = blockIdx.x * 4096;
  int t = threadIdx.x;
  int run = sums[blockIdx.x];
  for (int c = 0; c < 16; c++) {
    int idx = base + c * 256 + t;
    int v = (idx < n) ? cnt[idx] : 0;
    sd[t] = v; __syncthreads();
    for (int s = 1; s < 256; s <<= 1) {
      int u = (t >= s) ? sd[t - s] : 0;
      __syncthreads();
      sd[t] += u;
      __syncthreads();
    }
    if (idx < n) offs[idx] = run + sd[t] - v;  // exclusive
    run += sd[255];
    __syncthreads();
  }
  if (blockIdx.x == 0 && t == 0) offs[n] = E;
}

__global__ void k_scatter(const int* __restrict__ ei, const int* __restrict__ et,
                          int* __restrict__ cursor, int* __restrict__ pk, int E) {
  int e = blockIdx.x * 256 + threadIdx.x;
  if (e < E) {
    int s = ei[e];       // src < 50000 fits in 16 bits
    int d = ei[E + e];
    int t = et[e];
    int pos = atomicAdd(&cursor[d * NREL + t], 1);
    pk[pos] = s | (t << 16);
  }
}

// ======================= per-layer kernels =======================

// wq[r][c] = sum_d W[r][c][d]*q[d] ; wk likewise. 2048 outputs.
__global__ void k_wqk(const float* __restrict__ W, const float* __restrict__ q,
                      const float* __restrict__ k, float* __restrict__ wq,
                      float* __restrict__ wk) {
  int id = blockIdx.x * 256 + threadIdx.x;  // 0..2047
  if (id >= 2 * NREL * DIM) return;
  int which = id >> 10;       // 0 = q, 1 = k
  int rc = id & 1023;         // r*128 + c
  const float* wrow = W + (size_t)rc * DIM;
  const float* v = which ? k : q;
  float acc = 0.f;
#pragma unroll 8
  for (int d = 0; d < DIM; d++) acc += wrow[d] * v[d];
  (which ? wk : wq)[rc] = acc;
}

// qp[n][r] = x[n]·wq[r], kp[n][r] = x[n]·wk[r]. One wave per node.
__global__ void k_qk(const float* __restrict__ x, const float* __restrict__ wq,
                     const float* __restrict__ wk, float* __restrict__ qp,
                     float* __restrict__ kp, int N) {
  int wid = (blockIdx.x * blockDim.x + threadIdx.x) >> 6;
  int lane = threadIdx.x & 63;
  if (wid >= N) return;
  float x0 = x[(size_t)wid * DIM + lane];
  float x1 = x[(size_t)wid * DIM + 64 + lane];
#pragma unroll
  for (int r = 0; r < NREL; r++) {
    float aq = x0 * wq[r * DIM + lane] + x1 * wq[r * DIM + 64 + lane];
    float ak = x0 * wk[r * DIM + lane] + x1 * wk[r * DIM + 64 + lane];
    for (int s = 32; s > 0; s >>= 1) {
      aq += __shfl_xor(aq, s);
      ak += __shfl_xor(ak, s);
    }
    if (lane == 0) {
      qp[(size_t)wid * NREL + r] = aq;
      kp[(size_t)wid * NREL + r] = ak;
    }
  }
}

// Per-node: across-relation softmax over incoming edges, then per-relation
// aggregation s[n][r*128+c] = sum_e alpha_e * x[src_e][c]. One wave per node.
__global__ void k_agg(const float* __restrict__ x, const float* __restrict__ qp,
                      const float* __restrict__ kp, const int* __restrict__ offs,
                      const int* __restrict__ pk, float* __restrict__ s, int N) {
  int wid = (blockIdx.x * blockDim.x + threadIdx.x) >> 6;
  int lane = threadIdx.x & 63;
  if (wid >= N) return;
  int base = wid * NREL;
  int start = offs[base], end = offs[base + NREL];
  float* srow = s + (size_t)wid * (NREL * DIM);
  if (start == end) {  // no incoming edges: all-zero row
#pragma unroll
    for (int r = 0; r < NREL; r++) {
      srow[r * DIM + lane] = 0.f;
      srow[r * DIM + 64 + lane] = 0.f;
    }
    return;
  }
  // phase 1: max of leaky_relu(qp[dst,et] + kp[src,et])
  float m = -1e30f;
  for (int i = start + lane; i < end; i += 64) {
    int p = pk[i];
    int src = p & 0xffff, t = p >> 16;
    float a = qp[base + t] + kp[src * NREL + t];
    a = (a > 0.f) ? a : NEG_SLOPE * a;
    m = fmaxf(m, a);
  }
  for (int sft = 32; sft > 0; sft >>= 1) m = fmaxf(m, __shfl_xor(m, sft));
  // phase 2: sum of exp
  float ssum = 0.f;
  for (int i = start + lane; i < end; i += 64) {
    int p = pk[i];
    int src = p & 0xffff, t = p >> 16;
    float a = qp[base + t] + kp[src * NREL + t];
    a = (a > 0.f) ? a : NEG_SLOPE * a;
    ssum += expf(a - m);
  }
  for (int sft = 32; sft > 0; sft >>= 1) ssum += __shfl_xor(ssum, sft);
  float inv = 1.f / (ssum + 1e-16f);
  // phase 3: per-relation weighted aggregation (edges sorted by (dst, et))
#pragma unroll
  for (int r = 0; r < NREL; r++) {
    int e0 = offs[base + r], e1 = offs[base + r + 1];
    float qv = qp[base + r];
    float a0 = 0.f, a1 = 0.f;
    for (int i = e0; i < e1; ++i) {
      int p = pk[i];
      int src = p & 0xffff;
      float a = qv + kp[src * NREL + r];
      a = (a > 0.f) ? a : NEG_SLOPE * a;
      float wgt = expf(a - m) * inv;
      a0 += wgt * x[(size_t)src * DIM + lane];
      a1 += wgt * x[(size_t)src * DIM + 64 + lane];
    }
    srow[r * DIM + lane] = a0;
    srow[r * DIM + 64 + lane] = a1;
  }
}

// out[m][d] = relu_opt( sum_k s[m][k] * Wflat[k][d] + b[d] ), K=1024, N=128.
#define MT 64
#define KT 32
__global__ __launch_bounds__(256) void k_gemm(const float* __restrict__ s,
                                              const float* __restrict__ W,
                                              const float* __restrict__ b,
                                              float* __restrict__ out, int M,
                                              int relu) {
  __shared__ float sA[MT][KT + 1];    // [m][k], +1 pad
  __shared__ float sB[KT][DIM + 4];   // [k][n], +4 pad keeps 16B alignment
  int t = threadIdx.x;
  int tm = t >> 4, tn = t & 15;       // 16x16 thread grid; micro-tile 4x8
  int m0 = blockIdx.x * MT;
  float acc[4][8] = {};
  for (int k0 = 0; k0 < NREL * DIM; k0 += KT) {
    // load A tile 64x32 (2 float4 per thread)
    {
      int row = t >> 3;
      int col = (t & 7) * 4;
#pragma unroll
      for (int rr = 0; rr < 2; rr++) {
        int m = m0 + row + rr * 32;
        float4 v = make_float4(0.f, 0.f, 0.f, 0.f);
        if (m < M) v = *(const float4*)(s + (size_t)m * (NREL * DIM) + k0 + col);
        sA[row + rr * 32][col + 0] = v.x;
        sA[row + rr * 32][col + 1] = v.y;
        sA[row + rr * 32][col + 2] = v.z;
        sA[row + rr * 32][col + 3] = v.w;
      }
    }
    // load B tile 32x128 (4 float4 per thread)
    {
      int row = t >> 5;
      int col = (t & 31) * 4;
#pragma unroll
      for (int rr = 0; rr < 4; rr++) {
        float4 v = *(const float4*)(W + (size_t)(k0 + row + rr * 8) * DIM + col);
        *(float4*)(&sB[row + rr * 8][col]) = v;
      }
    }
    __syncthreads();
#pragma unroll
    for (int k = 0; k < KT; k++) {
      float a[4];
#pragma unroll
      for (int i = 0; i < 4; i++) a[i] = sA[tm * 4 + i][k];
      float4 b0 = *(float4*)(&sB[k][tn * 8]);
      float4 b1 = *(float4*)(&sB[k][tn * 8 + 4]);
      float bb[8] = {b0.x, b0.y, b0.z, b0.w, b1.x, b1.y, b1.z, b1.w};
#pragma unroll
      for (int i = 0; i < 4; i++)
#pragma unroll
        for (int j = 0; j < 8; j++) acc[i][j] += a[i] * bb[j];
    }
    __syncthreads();
  }
  // epilogue: bias (+ relu), vectorized store
#pragma unroll
  for (int i = 0; i < 4; i++) {
    int m = m0 + tm * 4 + i;
    if (m >= M) continue;
    float4 o0, o1;
    float* po = (float*)&o0;
#pragma unroll
    for (int j = 0; j < 8; j++) {
      float v = acc[i][j] + b[tn * 8 + j];
      if (relu) v = fmaxf(v, 0.f);
      if (j < 4) ((float*)&o0)[j] = v; else ((float*)&o1)[j - 4] = v;
    }
    (void)po;
    *(float4*)(out + (size_t)m * DIM + tn * 8) = o0;
    *(float4*)(out + (size_t)m * DIM + tn * 8 + 4) = o1;
  }
}

// ======================= launcher =======================

extern "C" void kernel_launch(void* const* d_in, const int* in_sizes, int n_in,
                              void* d_out, int out_size, void* d_ws, size_t ws_size,
                              hipStream_t stream) {
  const float* x = (const float*)d_in[0];
  const int* ei = (const int*)d_in[1];
  const int* et = (const int*)d_in[2];
  const float* Wl[3] = {(const float*)d_in[3], (const float*)d_in[7], (const float*)d_in[11]};
  const float* ql[3] = {(const float*)d_in[4], (const float*)d_in[8], (const float*)d_in[12]};
  const float* kl[3] = {(const float*)d_in[5], (const float*)d_in[9], (const float*)d_in[13]};
  const float* bl[3] = {(const float*)d_in[6], (const float*)d_in[10], (const float*)d_in[14]};
  float* out = (float*)d_out;

  char* w = (char*)d_ws;
  auto alloc = [&](size_t bytes) -> char* {
    char* p = w;
    w += (bytes + 255) & ~(size_t)255;
    return p;
  };
  const int NK = NNODES * NREL;
  int* cnt = (int*)alloc((size_t)NK * 4);
  int* offs = (int*)alloc((size_t)(NK + 1) * 4);
  int* cursor = (int*)alloc((size_t)NK * 4);
  int* sums = (int*)alloc(256 * 4);
  int* pk = (int*)alloc((size_t)NEDGES * 4);
  float* wq = (float*)alloc((size_t)NREL * DIM * 4);
  float* wk = (float*)alloc((size_t)NREL * DIM * 4);
  float* qp = (float*)alloc((size_t)NNODES * NREL * 4);
  float* kp = (float*)alloc((size_t)NNODES * NREL * 4);
  float* sbuf = (float*)alloc((size_t)NNODES * NREL * DIM * 4);
  float* h1 = (float*)alloc((size_t)NNODES * DIM * 4);
  float* h2 = (float*)alloc((size_t)NNODES * DIM * 4);

  // ---- build CSR sorted by (dst, etype), once (shared by all 3 layers) ----
  hipMemsetAsync(cnt, 0, (size_t)NK * 4, stream);
  k_hist<<<(NEDGES + 255) / 256, 256, 0, stream>>>(ei, et, cnt, NEDGES);
  int nchunk = (NK + 4095) / 4096;  // 98
  k_scan_reduce<<<nchunk, 256, 0, stream>>>(cnt, sums, NK);
  k_scan_top<<<1, 64, 0, stream>>>(sums, nchunk);
  k_scan_final<<<nchunk, 256, 0, stream>>>(cnt, sums, offs, NK, NEDGES);
  hipMemcpyAsync(cursor, offs, (size_t)NK * 4, hipMemcpyDeviceToDevice, stream);
  k_scatter<<<(NEDGES + 255) / 256, 256, 0, stream>>>(ei, et, cursor, pk, NEDGES);

  // ---- 3 RGAT layers ----
  const float* hin = x;
  float* houts[3] = {h1, h2, out};
  for (int l = 0; l < 3; l++) {
    k_wqk<<<(2 * NREL * DIM + 255) / 256, 256, 0, stream>>>(Wl[l], ql[l], kl[l], wq, wk);
    k_qk<<<(NNODES + 3) / 4, 256, 0, stream>>>(hin, wq, wk, qp, kp, NNODES);
    k_agg<<<(NNODES + 3) / 4, 256, 0, stream>>>(hin, qp, kp, offs, pk, sbuf, NNODES);
    k_gemm<<<(NNODES + MT - 1) / MT, 256, 0, stream>>>(sbuf, Wl[l], bl[l], houts[l],
                                                       NNODES, l < 2 ? 1 : 0);
    hin = houts[l];
  }
}

// Round 2
// 976.339 us; speedup vs baseline: 1.4457x; 1.4457x over previous
//
#include <hip/hip_runtime.h>
#include <hip/hip_bf16.h>
#include <cstdint>
#include <cstddef>

#define NNODES 50000
#define NEDGES 800000
#define NREL 8
#define DIM 128
#define KDIM (NREL * DIM)  // 1024
#define NEG_SLOPE 0.2f

typedef __attribute__((ext_vector_type(8))) short short8;
typedef __attribute__((ext_vector_type(4))) float f32x4;

// ======================= preprocessing: CSR by (dst, etype) =======================

__global__ void k_hist(const int* __restrict__ ei, const int* __restrict__ et,
                       int* __restrict__ cnt, int E) {
  int e = blockIdx.x * 256 + threadIdx.x;
  if (e < E) {
    int d = ei[E + e];
    int t = et[e];
    atomicAdd(&cnt[d * NREL + t], 1);
  }
}

__global__ void k_scan_reduce(const int* __restrict__ cnt, int* __restrict__ sums, int n) {
  __shared__ int sd[256];
  int base = blockIdx.x * 4096;
  int t = threadIdx.x;
  int acc = 0;
  for (int i = t; i < 4096; i += 256) {
    int idx = base + i;
    if (idx < n) acc += cnt[idx];
  }
  sd[t] = acc; __syncthreads();
  for (int s = 128; s > 0; s >>= 1) {
    if (t < s) sd[t] += sd[t + s];
    __syncthreads();
  }
  if (t == 0) sums[blockIdx.x] = sd[0];
}

__global__ void k_scan_top(int* sums, int nb) {
  if (threadIdx.x == 0 && blockIdx.x == 0) {
    int run = 0;
    for (int i = 0; i < nb; i++) { int v = sums[i]; sums[i] = run; run += v; }
  }
}

__global__ void k_scan_final(const int* __restrict__ cnt, const int* __restrict__ sums,
                             int* __restrict__ offs, int n, int E) {
  __shared__ int sd[256];
  int base = blockIdx.x * 4096;
  int t = threadIdx.x;
  int run = sums[blockIdx.x];
  for (int c = 0; c < 16; c++) {
    int idx = base + c * 256 + t;
    int v = (idx < n) ? cnt[idx] : 0;
    sd[t] = v; __syncthreads();
    for (int s = 1; s < 256; s <<= 1) {
      int u = (t >= s) ? sd[t - s] : 0;
      __syncthreads();
      sd[t] += u;
      __syncthreads();
    }
    if (idx < n) offs[idx] = run + sd[t] - v;  // exclusive
    run += sd[255];
    __syncthreads();
  }
  if (blockIdx.x == 0 && t == 0) offs[n] = E;
}

__global__ void k_scatter(const int* __restrict__ ei, const int* __restrict__ et,
                          int* __restrict__ cursor, int* __restrict__ pk, int E) {
  int e = blockIdx.x * 256 + threadIdx.x;
  if (e < E) {
    int s = ei[e];       // src < 50000 fits in 16 bits
    int d = ei[E + e];
    int t = et[e];
    int pos = atomicAdd(&cursor[d * NREL + t], 1);
    pk[pos] = s | (t << 16);
  }
}

// ======================= per-layer kernels =======================

// Split W [1024,128] fp32 into transposed bf16 hi/lo planes [128][1024] (n-major).
__global__ void k_splitW(const float* __restrict__ W, __hip_bfloat16* __restrict__ wht,
                         __hip_bfloat16* __restrict__ wlt) {
  int id = blockIdx.x * 256 + threadIdx.x;  // = k*128 + n
  if (id >= KDIM * DIM) return;
  int k = id >> 7, n = id & 127;
  float v = W[id];
  __hip_bfloat16 h = __float2bfloat16(v);
  float hv = __bfloat162float(h);
  wht[(size_t)n * KDIM + k] = h;
  wlt[(size_t)n * KDIM + k] = __float2bfloat16(v - hv);
}

// wq[r][c] = sum_d W[r][c][d]*q[d] ; wk likewise. 2048 outputs.
__global__ void k_wqk(const float* __restrict__ W, const float* __restrict__ q,
                      const float* __restrict__ k, float* __restrict__ wq,
                      float* __restrict__ wk) {
  int id = blockIdx.x * 256 + threadIdx.x;  // 0..2047
  if (id >= 2 * NREL * DIM) return;
  int which = id >> 10;       // 0 = q, 1 = k
  int rc = id & 1023;         // r*128 + c
  const float* wrow = W + (size_t)rc * DIM;
  const float* v = which ? k : q;
  float acc = 0.f;
#pragma unroll 8
  for (int d = 0; d < DIM; d++) acc += wrow[d] * v[d];
  (which ? wk : wq)[rc] = acc;
}

// qp[n][r] = x[n]·wq[r], kp[n][r] = x[n]·wk[r]. One wave per node.
__global__ void k_qk(const float* __restrict__ x, const float* __restrict__ wq,
                     const float* __restrict__ wk, float* __restrict__ qp,
                     float* __restrict__ kp, int N) {
  int wid = (blockIdx.x * blockDim.x + threadIdx.x) >> 6;
  int lane = threadIdx.x & 63;
  if (wid >= N) return;
  float x0 = x[(size_t)wid * DIM + lane];
  float x1 = x[(size_t)wid * DIM + 64 + lane];
#pragma unroll
  for (int r = 0; r < NREL; r++) {
    float aq = x0 * wq[r * DIM + lane] + x1 * wq[r * DIM + 64 + lane];
    float ak = x0 * wk[r * DIM + lane] + x1 * wk[r * DIM + 64 + lane];
    for (int s = 32; s > 0; s >>= 1) {
      aq += __shfl_xor(aq, s);
      ak += __shfl_xor(ak, s);
    }
    if (lane == 0) {
      qp[(size_t)wid * NREL + r] = aq;
      kp[(size_t)wid * NREL + r] = ak;
    }
  }
}

// Per-node: across-relation softmax over incoming edges, then per-relation
// aggregation s[n][r*128+c] = sum_e alpha_e * x[src_e][c], written as
// split-bf16 hi/lo planes [N][1024]. One wave per node.
__global__ void k_agg(const float* __restrict__ x, const float* __restrict__ qp,
                      const float* __restrict__ kp, const int* __restrict__ offs,
                      const int* __restrict__ pk, __hip_bfloat16* __restrict__ sbh,
                      __hip_bfloat16* __restrict__ sbl, int N) {
  int wid = (blockIdx.x * blockDim.x + threadIdx.x) >> 6;
  int lane = threadIdx.x & 63;
  if (wid >= N) return;
  int base = wid * NREL;
  int start = offs[base], end = offs[base + NREL];
  __hip_bfloat16* sh = sbh + (size_t)wid * KDIM;
  __hip_bfloat16* sl = sbl + (size_t)wid * KDIM;
  __hip_bfloat16 z = __float2bfloat16(0.f);
  if (start == end) {  // no incoming edges: all-zero row
#pragma unroll
    for (int r = 0; r < NREL; r++) {
      sh[r * DIM + lane] = z;       sh[r * DIM + 64 + lane] = z;
      sl[r * DIM + lane] = z;       sl[r * DIM + 64 + lane] = z;
    }
    return;
  }
  // phase 1: max of leaky_relu(qp[dst,et] + kp[src,et])
  float m = -1e30f;
  for (int i = start + lane; i < end; i += 64) {
    int p = pk[i];
    int src = p & 0xffff, t = p >> 16;
    float a = qp[base + t] + kp[src * NREL + t];
    a = (a > 0.f) ? a : NEG_SLOPE * a;
    m = fmaxf(m, a);
  }
  for (int sft = 32; sft > 0; sft >>= 1) m = fmaxf(m, __shfl_xor(m, sft));
  // phase 2: sum of exp
  float ssum = 0.f;
  for (int i = start + lane; i < end; i += 64) {
    int p = pk[i];
    int src = p & 0xffff, t = p >> 16;
    float a = qp[base + t] + kp[src * NREL + t];
    a = (a > 0.f) ? a : NEG_SLOPE * a;
    ssum += expf(a - m);
  }
  for (int sft = 32; sft > 0; sft >>= 1) ssum += __shfl_xor(ssum, sft);
  float inv = 1.f / (ssum + 1e-16f);
  // phase 3: per-relation weighted aggregation (edges sorted by (dst, et))
#pragma unroll
  for (int r = 0; r < NREL; r++) {
    int e0 = offs[base + r], e1 = offs[base + r + 1];
    float qv = qp[base + r];
    float a0 = 0.f, a1 = 0.f;
    for (int i = e0; i < e1; ++i) {
      int p = pk[i];
      int src = p & 0xffff;
      float a = qv + kp[src * NREL + r];
      a = (a > 0.f) ? a : NEG_SLOPE * a;
      float wgt = expf(a - m) * inv;
      a0 += wgt * x[(size_t)src * DIM + lane];
      a1 += wgt * x[(size_t)src * DIM + 64 + lane];
    }
    {
      __hip_bfloat16 h0 = __float2bfloat16(a0);
      sh[r * DIM + lane] = h0;
      sl[r * DIM + lane] = __float2bfloat16(a0 - __bfloat162float(h0));
      __hip_bfloat16 h1 = __float2bfloat16(a1);
      sh[r * DIM + 64 + lane] = h1;
      sl[r * DIM + 64 + lane] = __float2bfloat16(a1 - __bfloat162float(h1));
    }
  }
}

// ======================= split-bf16 MFMA GEMM =======================
// out[m][n] = relu_opt( sum_k A[m][k]*W[k][n] + bias[n] ),  M=50000, K=1024, N=128.
// Computed as C^T via mfma: A-operand = W^T (n-major splits), B-operand = A^T.
// 3-term split: hh + hl + lh.
#define GM 64
#define ROWB 80  // padded LDS row stride in bytes (40 shorts): 16B-aligned, bank-stride 20

__global__ __launch_bounds__(256, 3) void k_gemm_mfma(
    const __hip_bfloat16* __restrict__ Ah, const __hip_bfloat16* __restrict__ Al,  // [M][1024]
    const __hip_bfloat16* __restrict__ Wh, const __hip_bfloat16* __restrict__ Wl,  // [128][1024]
    const float* __restrict__ bias, float* __restrict__ out, int M, int relu) {
  __shared__ char sAh[GM * ROWB], sAl[GM * ROWB];
  __shared__ char sWh[DIM * ROWB], sWl[DIM * ROWB];
  int t = threadIdx.x;
  int w = t >> 6, l = t & 63;
  int m0 = blockIdx.x * GM;

  f32x4 acc[4][2];
  f32x4 zero = {0.f, 0.f, 0.f, 0.f};
#pragma unroll
  for (int mt = 0; mt < 4; mt++)
#pragma unroll
    for (int nt = 0; nt < 2; nt++) acc[mt][nt] = zero;

  int srow = t >> 2;   // 0..63
  int sseg = t & 3;    // 0..3  (16B chunk within 64B tile-row)

  for (int k0 = 0; k0 < KDIM; k0 += 32) {
    // ---- stage A hi/lo: 64 rows x 64B each ----
    {
      int m = m0 + srow;
      float4 vh = make_float4(0.f, 0.f, 0.f, 0.f), vl = vh;
      if (m < M) {
        const char* ph = (const char*)Ah + (size_t)m * 2048 + k0 * 2 + sseg * 16;
        const char* pl = (const char*)Al + (size_t)m * 2048 + k0 * 2 + sseg * 16;
        vh = *(const float4*)ph;
        vl = *(const float4*)pl;
      }
      *(float4*)(sAh + srow * ROWB + sseg * 16) = vh;
      *(float4*)(sAl + srow * ROWB + sseg * 16) = vl;
    }
    // ---- stage W^T hi/lo: 128 rows x 64B each ----
#pragma unroll
    for (int rr = 0; rr < 2; rr++) {
      int n = srow + rr * 64;
      const char* ph = (const char*)Wh + (size_t)n * 2048 + k0 * 2 + sseg * 16;
      const char* pl = (const char*)Wl + (size_t)n * 2048 + k0 * 2 + sseg * 16;
      float4 vh = *(const float4*)ph;
      float4 vl = *(const float4*)pl;
      *(float4*)(sWh + n * ROWB + sseg * 16) = vh;
      *(float4*)(sWl + n * ROWB + sseg * 16) = vl;
    }
    __syncthreads();
    // ---- fragments + MFMA ----
    int kseg = (l >> 4) * 16;  // byte offset of this lane's 8 shorts within a row
    int r16 = l & 15;
    short8 fwh[2], fwl[2], fsh[4], fsl[4];
#pragma unroll
    for (int nt = 0; nt < 2; nt++) {
      int n = w * 32 + nt * 16 + r16;
      fwh[nt] = *(const short8*)(sWh + n * ROWB + kseg);
      fwl[nt] = *(const short8*)(sWl + n * ROWB + kseg);
    }
#pragma unroll
    for (int mt = 0; mt < 4; mt++) {
      int m = mt * 16 + r16;
      fsh[mt] = *(const short8*)(sAh + m * ROWB + kseg);
      fsl[mt] = *(const short8*)(sAl + m * ROWB + kseg);
    }
#pragma unroll
    for (int mt = 0; mt < 4; mt++)
#pragma unroll
      for (int nt = 0; nt < 2; nt++) {
        acc[mt][nt] = __builtin_amdgcn_mfma_f32_16x16x32_bf16(fwh[nt], fsh[mt], acc[mt][nt], 0, 0, 0);
        acc[mt][nt] = __builtin_amdgcn_mfma_f32_16x16x32_bf16(fwh[nt], fsl[mt], acc[mt][nt], 0, 0, 0);
        acc[mt][nt] = __builtin_amdgcn_mfma_f32_16x16x32_bf16(fwl[nt], fsh[mt], acc[mt][nt], 0, 0, 0);
      }
    __syncthreads();
  }
  // ---- epilogue: D col(l&15) = m offset, D row((l>>4)*4+i) = n offset ----
  int r16 = l & 15, rh = l >> 4;
#pragma unroll
  for (int mt = 0; mt < 4; mt++) {
    int m = m0 + mt * 16 + r16;
    if (m >= M) continue;
#pragma unroll
    for (int nt = 0; nt < 2; nt++) {
      int n = w * 32 + nt * 16 + rh * 4;
      float4 bv = *(const float4*)(bias + n);
      f32x4 a = acc[mt][nt];
      float4 o;
      o.x = a.x + bv.x; o.y = a.y + bv.y; o.z = a.z + bv.z; o.w = a.w + bv.w;
      if (relu) {
        o.x = fmaxf(o.x, 0.f); o.y = fmaxf(o.y, 0.f);
        o.z = fmaxf(o.z, 0.f); o.w = fmaxf(o.w, 0.f);
      }
      *(float4*)(out + (size_t)m * DIM + n) = o;
    }
  }
}

// ======================= launcher =======================

extern "C" void kernel_launch(void* const* d_in, const int* in_sizes, int n_in,
                              void* d_out, int out_size, void* d_ws, size_t ws_size,
                              hipStream_t stream) {
  const float* x = (const float*)d_in[0];
  const int* ei = (const int*)d_in[1];
  const int* et = (const int*)d_in[2];
  const float* Wl3[3] = {(const float*)d_in[3], (const float*)d_in[7], (const float*)d_in[11]};
  const float* ql[3] = {(const float*)d_in[4], (const float*)d_in[8], (const float*)d_in[12]};
  const float* kl[3] = {(const float*)d_in[5], (const float*)d_in[9], (const float*)d_in[13]};
  const float* bl[3] = {(const float*)d_in[6], (const float*)d_in[10], (const float*)d_in[14]};
  float* out = (float*)d_out;

  char* w = (char*)d_ws;
  auto alloc = [&](size_t bytes) -> char* {
    char* p = w;
    w += (bytes + 255) & ~(size_t)255;
    return p;
  };
  const int NK = NNODES * NREL;
  int* cnt = (int*)alloc((size_t)NK * 4);
  int* offs = (int*)alloc((size_t)(NK + 1) * 4);
  int* cursor = (int*)alloc((size_t)NK * 4);
  int* sums = (int*)alloc(256 * 4);
  int* pk = (int*)alloc((size_t)NEDGES * 4);
  float* wq = (float*)alloc((size_t)NREL * DIM * 4);
  float* wk = (float*)alloc((size_t)NREL * DIM * 4);
  float* qp = (float*)alloc((size_t)NNODES * NREL * 4);
  float* kp = (float*)alloc((size_t)NNODES * NREL * 4);
  __hip_bfloat16* sbh = (__hip_bfloat16*)alloc((size_t)NNODES * KDIM * 2);
  __hip_bfloat16* sbl = (__hip_bfloat16*)alloc((size_t)NNODES * KDIM * 2);
  __hip_bfloat16* wht = (__hip_bfloat16*)alloc((size_t)DIM * KDIM * 2);
  __hip_bfloat16* wlt = (__hip_bfloat16*)alloc((size_t)DIM * KDIM * 2);
  float* h1 = (float*)alloc((size_t)NNODES * DIM * 4);
  float* h2 = (float*)alloc((size_t)NNODES * DIM * 4);

  // ---- build CSR sorted by (dst, etype), once (shared by all 3 layers) ----
  hipMemsetAsync(cnt, 0, (size_t)NK * 4, stream);
  k_hist<<<(NEDGES + 255) / 256, 256, 0, stream>>>(ei, et, cnt, NEDGES);
  int nchunk = (NK + 4095) / 4096;  // 98
  k_scan_reduce<<<nchunk, 256, 0, stream>>>(cnt, sums, NK);
  k_scan_top<<<1, 64, 0, stream>>>(sums, nchunk);
  k_scan_final<<<nchunk, 256, 0, stream>>>(cnt, sums, offs, NK, NEDGES);
  hipMemcpyAsync(cursor, offs, (size_t)NK * 4, hipMemcpyDeviceToDevice, stream);
  k_scatter<<<(NEDGES + 255) / 256, 256, 0, stream>>>(ei, et, cursor, pk, NEDGES);

  // ---- 3 RGAT layers ----
  const float* hin = x;
  float* houts[3] = {h1, h2, out};
  for (int l = 0; l < 3; l++) {
    k_splitW<<<(KDIM * DIM + 255) / 256, 256, 0, stream>>>(Wl3[l], wht, wlt);
    k_wqk<<<(2 * NREL * DIM + 255) / 256, 256, 0, stream>>>(Wl3[l], ql[l], kl[l], wq, wk);
    k_qk<<<(NNODES + 3) / 4, 256, 0, stream>>>(hin, wq, wk, qp, kp, NNODES);
    k_agg<<<(NNODES + 3) / 4, 256, 0, stream>>>(hin, qp, kp, offs, pk, sbh, sbl, NNODES);
    k_gemm_mfma<<<(NNODES + GM - 1) / GM, 256, 0, stream>>>(sbh, sbl, wht, wlt, bl[l],
                                                            houts[l], NNODES, l < 2 ? 1 : 0);
    hin = houts[l];
  }
}